// Round 6
// baseline (95.938 us; speedup 1.0000x reference)
//
#include <hip/hip_runtime.h>

// ConvCapsuleLayer: B=2, 48x48, IN_CAPS=8, ATOMS=16, KER=3, OUT_CAPS=16, R=3.
// Round-17: 2 pixels per 256-thread block (2116 blocks). Evidence: wave-issue
// fraction ~16% (VALUBusy 52% / 3.2 waves/SIMD) -> latency-bound, ILP-starved;
// residency knobs (r13/14) and LDS-traffic cuts (r16) both proven neutral.
// Interleaving two independent per-pixel instruction streams doubles ILP in
// every barrier-to-barrier segment, halves barriers/pixel, and load-balances
// the fused phase across waves (px0 on tid<144, px1 on tid>=112:
// per-wave fused load {64,80,80,64} vs {128,128,32,0}).
//  - registers: ~100-110 VGPR under __launch_bounds__(256,3) budget 170
//    (r12/r16 lesson: spill guard = WRITE_SIZE must stay ~4.2MB).
//  - LDS 2x = 52.5KB -> 3 blocks/CU (measured residency was ~3 anyway).
//  - pair-level bijective XCD swizzle (2116 = 8*264+4, m204 formula);
//    adjacent pixels share 6/9 patch columns -> L1/L2 reuse.
//  - keeps r15 r=0 specialization; keeps r16 2-hop squash (VGPR-neutral).

#define IN_CAPS 8
#define OUT_CAPS 16
#define KK 9
#define KKIN 72
#define BATCH 2
#define H_IN 48
#define W_IN 48
#define HO 46
#define WO 46
#define CIN 136
#define NPIX (BATCH*HO*WO)   // 4232
#define NPAIR (NPIX/2)       // 2116 = 8*264 + 4

typedef float v2f __attribute__((ext_vector_type(2)));
typedef float v4f __attribute__((ext_vector_type(4)));

__device__ __forceinline__ v2f lo2(v4f v) { return __builtin_shufflevector(v, v, 0, 1); }
__device__ __forceinline__ v2f hi2(v4f v) { return __builtin_shufflevector(v, v, 2, 3); }
__device__ __forceinline__ v2f fma2(v2f a, v2f b, v2f c) {
    return __builtin_elementwise_fma(a, b, c);
}

template<int CTRL>
__device__ __forceinline__ float dpp_f(float x) {
    return __int_as_float(
        __builtin_amdgcn_update_dpp(0, __float_as_int(x), CTRL, 0xF, 0xF, true));
}

// pose_s row start: stride 20 + skew in {0,4} (round-11 verified layout)
__device__ __forceinline__ int pose_row(int k) {
    return k * 20 + ((k >> 3) & 1) * 4;
}
// G row start for (o, ic): stride 20 rows + 4*o skew (round-11 verified)
__device__ __forceinline__ int g_row(int o, int ic) {
    return (o * 8 + ic) * 20 + o * 4;
}

__global__ __launch_bounds__(256, 3)
void capsule_routing_kernel(const float* __restrict__ x,
                            const float* __restrict__ Wg,
                            float* __restrict__ out)
{
    __shared__ alignas(16) float pose_s[2][1440];          // 11520 B
    __shared__ alignas(16) float pose_t[2][16 * 76];       //  9728 B
    __shared__ alignas(16) float act_s[2][KKIN];           //   576 B
    __shared__ alignas(16) float g_s[2][2620];             // 20960 B
    __shared__ alignas(16) float coup_s[2][OUT_CAPS * 76]; //  9728 B
    // total 52512 B -> 3 blocks/CU

    const int tid = threadIdx.x;
    const int o = tid >> 4;        // out capsule
    const int e = tid & 15;        // atom = a*4+c
    const int c = e & 3;

    // bijective chunked XCD swizzle over 2116 pairs (q=264, r=4):
    const int bx  = blockIdx.x;
    const int xcd = bx & 7;
    const int sub = bx >> 3;
    const int pair = (xcd < 4 ? xcd * 265 : 1060 + (xcd - 4) * 264) + sub;
    const int n0 = pair * 2;
    const int n1 = n0 + 1;

    // ---- W row fragment (shared by both pixels):
    //      w01[ic] = (W[ic][o][c][0], W[ic][o][c][1]), w23 = ([2],[3]) ----
    v2f w01[IN_CAPS], w23[IN_CAPS];
    #pragma unroll
    for (int i = 0; i < IN_CAPS; ++i) {
        const v4f wv = *reinterpret_cast<const v4f*>(
            &Wg[((i * OUT_CAPS + o) * 4 + c) * 4]);
        w01[i] = lo2(wv);
        w23[i] = hi2(wv);
    }

    // ---- load both pixels' 3x3 patches ----
    #pragma unroll
    for (int p01 = 0; p01 < 2; ++p01) {
        const int nn  = p01 ? n1 : n0;
        const int b   = nn / (HO * WO);
        const int rem = nn - b * (HO * WO);
        const int ho  = rem / WO;
        const int wo  = rem - ho * WO;
        for (int idx = tid; idx < KK * CIN; idx += 256) {
            int p  = idx / CIN;
            int cc = idx - p * CIN;
            int py = p / 3, px = p - py * 3;
            float val = x[(((b * H_IN + ho + py) * W_IN) + (wo + px)) * CIN + cc];
            int ic = cc / 17;
            int aa = cc - ic * 17;
            int k  = p * IN_CAPS + ic;
            if (aa == 16) {
                act_s[p01][k] = val;
            } else {
                pose_s[p01][pose_row(k) + aa] = val;
                pose_t[p01][aa * 76 + k] = val;
            }
        }
    }
    __syncthreads();

    float lr0[8] = {0.f,0.f,0.f,0.f,0.f,0.f,0.f,0.f};
    float lr1[8] = {0.f,0.f,0.f,0.f,0.f,0.f,0.f,0.f};

    const v4f* cp0 = reinterpret_cast<const v4f*>(&coup_s[0][o * 76]);
    const v4f* cp1 = reinterpret_cast<const v4f*>(&coup_s[1][o * 76]);
    const v4f* pp0 = reinterpret_cast<const v4f*>(&pose_t[0][e * 76]);
    const v4f* pp1 = reinterpret_cast<const v4f*>(&pose_t[1][e * 76]);
    const v4f* ap0 = reinterpret_cast<const v4f*>(act_s[0]);
    const v4f* ap1 = reinterpret_cast<const v4f*>(act_s[1]);

    // phase B + U + quad-allreduce + squash for one pixel -> v
    auto phaseB = [&](const v4f* ca, const v4f* qa, float mscale) -> float {
        v2f M01 = {0.f,0.f}, M23 = {0.f,0.f}, M45 = {0.f,0.f}, M67 = {0.f,0.f};
        #pragma unroll
        for (int p = 0; p < KK; ++p) {
            const v4f c0 = ca[2*p], c1 = ca[2*p+1];
            const v4f q0 = qa[2*p], q1 = qa[2*p+1];
            M01 = fma2(lo2(c0), lo2(q0), M01);
            M23 = fma2(hi2(c0), hi2(q0), M23);
            M45 = fma2(lo2(c1), lo2(q1), M45);
            M67 = fma2(hi2(c1), hi2(q1), M67);
        }
        const float Mc[8] = {M01.x, M01.y, M23.x, M23.y,
                             M45.x, M45.y, M67.x, M67.y};
        v2f U01 = {0.f,0.f}, U23 = {0.f,0.f};
        #pragma unroll
        for (int ic = 0; ic < 8; ++ic) {
            const v2f mm = {Mc[ic], Mc[ic]};
            U01 = fma2(w01[ic], mm, U01);
            U23 = fma2(w23[ic], mm, U23);
        }
        const v2f sc = {mscale, mscale};
        U01 *= sc; U23 *= sc;
        float Z0 = U01.x, Z1 = U01.y, Z2 = U23.x, Z3 = U23.y;
        Z0 += dpp_f<0xB1>(Z0); Z1 += dpp_f<0xB1>(Z1);
        Z2 += dpp_f<0xB1>(Z2); Z3 += dpp_f<0xB1>(Z3);
        Z0 += dpp_f<0x4E>(Z0); Z1 += dpp_f<0x4E>(Z1);
        Z2 += dpp_f<0x4E>(Z2); Z3 += dpp_f<0x4E>(Z3);
        float t = Z0*Z0 + Z1*Z1 + Z2*Z2 + Z3*Z3;
        t += dpp_f<0x124>(t);   // row_ror:4
        t += dpp_f<0x128>(t);   // row_ror:8
        const float s = (c == 0) ? Z0 : (c == 1) ? Z1 : (c == 2) ? Z2 : Z3;
        return s * (t / ((1.f + t) * sqrtf(t + 1e-7f)));
    };

    // G build for one pixel (registers only + 8 LDS stores)
    auto build_G = [&](int px, float v) {
        const float vq0 = dpp_f<0x00>(v);
        const float vq1 = dpp_f<0x55>(v);
        const float vq2 = dpp_f<0xAA>(v);
        const float vq3 = dpp_f<0xFF>(v);
        const v2f vq01 = {vq0, vq1};
        const v2f vq23 = {vq2, vq3};
        #pragma unroll
        for (int ic = 0; ic < 8; ++ic) {
            v2f h = fma2(w23[ic], vq23, w01[ic] * vq01);
            g_s[px][g_row(o, ic) + e] = h.x + h.y;
        }
    };

    // fused logit-update + softmax + coup write for one pixel
    auto fused = [&](int px, int kf, int hf, float (&lreg)[8]) {
        const int ick = kf & 7;
        const v4f* pk = reinterpret_cast<const v4f*>(&pose_s[px][pose_row(kf)]);
        const v4f p0 = pk[0], p1 = pk[1], p2 = pk[2], p3 = pk[3];
        const v2f q0 = lo2(p0), q1 = hi2(p0), q2 = lo2(p1), q3 = hi2(p1);
        const v2f q4 = lo2(p2), q5 = hi2(p2), q6 = lo2(p3), q7 = hi2(p3);
        float lg[8];
        #pragma unroll
        for (int j = 0; j < 8; ++j) {
            const int oo = hf * 8 + j;
            const v4f* gp = reinterpret_cast<const v4f*>(&g_s[px][g_row(oo, ick)]);
            const v4f g0 = gp[0], g1 = gp[1], g2 = gp[2], g3 = gp[3];
            v2f A = fma2(q2, lo2(g1), fma2(q4, lo2(g2),
                      fma2(q6, lo2(g3), q0 * lo2(g0))));
            v2f Bv = fma2(q3, hi2(g1), fma2(q5, hi2(g2),
                      fma2(q7, hi2(g3), q1 * hi2(g0))));
            lreg[j] += (A.x + A.y) + (Bv.x + Bv.y);
            lg[j] = lreg[j];
        }
        float mx = -1e30f;
        #pragma unroll
        for (int j = 0; j < 8; ++j) mx = fmaxf(mx, lg[j]);
        mx = fmaxf(mx, dpp_f<0xB1>(mx));
        float sum = 0.f;
        #pragma unroll
        for (int j = 0; j < 8; ++j) { lg[j] = __expf(lg[j] - mx); sum += lg[j]; }
        sum += dpp_f<0xB1>(sum);
        const float scale = act_s[px][kf] / sum;
        #pragma unroll
        for (int j = 0; j < 8; ++j)
            coup_s[px][(hf * 8 + j) * 76 + kf] = lg[j] * scale;
    };

    float v0, v1;

    // ===== r = 0 (coup = act/16, o-independent) =====
    v0 = phaseB(ap0, pp0, 0.0625f);
    v1 = phaseB(ap1, pp1, 0.0625f);
    build_G(0, v0);
    build_G(1, v1);
    __syncthreads();
    if (tid < 2 * KKIN)  fused(0, tid >> 1, tid & 1, lr0);
    if (tid >= 112) { const int t1 = tid - 112; fused(1, t1 >> 1, t1 & 1, lr1); }
    __syncthreads();

    // ===== r = 1 =====
    v0 = phaseB(cp0, pp0, 1.0f);
    v1 = phaseB(cp1, pp1, 1.0f);
    build_G(0, v0);
    build_G(1, v1);
    __syncthreads();
    if (tid < 2 * KKIN)  fused(0, tid >> 1, tid & 1, lr0);
    if (tid >= 112) { const int t1 = tid - 112; fused(1, t1 >> 1, t1 & 1, lr1); }
    __syncthreads();

    // ===== r = 2 (final) =====
    v0 = phaseB(cp0, pp0, 1.0f);
    v1 = phaseB(cp1, pp1, 1.0f);

    // ---- out[n][o][e], coalesced, both pixels ----
    out[n0 * 256 + tid] = v0;
    out[n1 * 256 + tid] = v1;
}

extern "C" void kernel_launch(void* const* d_in, const int* in_sizes, int n_in,
                              void* d_out, int out_size, void* d_ws, size_t ws_size,
                              hipStream_t stream) {
    const float* x  = (const float*)d_in[0];   // [2,48,48,136] fp32
    const float* Wt = (const float*)d_in[1];   // [8,16,4,4]    fp32
    float* outp = (float*)d_out;               // [2,46,46,16,16] fp32
    capsule_routing_kernel<<<dim3(NPAIR), dim3(256), 0, stream>>>(x, Wt, outp);
}

// Round 7
// 95.175 us; speedup vs baseline: 1.0080x; 1.0080x over previous
//
#include <hip/hip_runtime.h>

// ConvCapsuleLayer: B=2, 48x48, IN_CAPS=8, ATOMS=16, KER=3, OUT_CAPS=16, R=3.
// Round-18: WAVE-PER-PIXEL, ZERO BARRIERS. Evidence: per-wave issue duty ~17%
// (VALUBusy 52% / 3.2 waves/SIMD); residency (r13/14), LDS traffic (r16) and
// 2px-ILP (r17) all neutral-negative because the 4-wave barrier lockstep is
// the wall. New structure: lane=(o=l>>2, c=l&3); quad-allreduce over c gives
// each lane the FULL s[o,:,:] -> squash and G-build lane-local; the k-side
// transpose (logits/softmax/coup) stays in-wave via LDS + lgkmcnt(0) fences.
// 4 independent waves per block = 4 pixels; no __syncthreads anywhere.
//  - fused: k=lane (64) + tail k=64..71 redistributed (lane>>3 -> k,
//    (lane&7)*2 -> o-pair): all 64 lanes busy, softmax via 8-lane ds_swizzle
//    xor-reduce. No divergence.
//  - per-pixel LDS exactly 5120 floats: pose_t 16x76 + act[72] @1216 (1288),
//    coup 16x76 (1216), G skewed (2616) -> block 81920 B = 2 blocks/CU.
//  - all LDS patterns broadcast or <=2-way (checked per-instruction).
//  - keeps r15 r=0 specialization (coup==act/16 -> read act directly) and
//    XCD chunk swizzle (1058 = 8*132+2 bijective).
// Guard: WRITE_SIZE must stay ~4.2MB (no spill); FETCH ~1.5MB.

#define NPIX 4232
#define NBLK 1058   // 4 pixels/block, 1 per wave

typedef float v2f __attribute__((ext_vector_type(2)));
typedef float v4f __attribute__((ext_vector_type(4)));

__device__ __forceinline__ v2f lo2(v4f v) { return __builtin_shufflevector(v, v, 0, 1); }
__device__ __forceinline__ v2f hi2(v4f v) { return __builtin_shufflevector(v, v, 2, 3); }
__device__ __forceinline__ v2f fma2(v2f a, v2f b, v2f c) {
    return __builtin_elementwise_fma(a, b, c);
}

template<int CTRL>
__device__ __forceinline__ float dpp_f(float x) {
    return __int_as_float(
        __builtin_amdgcn_update_dpp(0, __float_as_int(x), CTRL, 0xF, 0xF, true));
}
template<int OFF>
__device__ __forceinline__ float swz(float x) {
    return __int_as_float(__builtin_amdgcn_ds_swizzle(__float_as_int(x), OFF));
}

// G row start for (o, ic): stride 20 rows + 4*o skew (round-11 verified).
// stores (per (ic,a) instr): banks (4o+20ic+4a+c)%32 -> 2-way. reads (fused):
// 8 ic-groups x 8-lane broadcast, bases 20ic%32 all distinct -> conflict-free.
__device__ __forceinline__ int g_row(int o, int ic) {
    return (o * 8 + ic) * 20 + o * 4;
}

__global__ __launch_bounds__(256, 2)
void capsule_routing_kernel(const float* __restrict__ x,
                            const float* __restrict__ Wg,
                            float* __restrict__ out)
{
    // per-pixel: pose_t rows [aa][k] stride 76 (1216) + act[72] @1216 -> 1288
    __shared__ alignas(16) float pose_t[4][1288];   // 20608 B
    __shared__ alignas(16) float coup_s[4][1216];   // 19456 B
    __shared__ alignas(16) float g_s[4][2616];      // 41856 B
    // total 81920 B exactly -> 2 blocks/CU (8 independent waves)

    const int tid  = threadIdx.x;
    const int wid  = tid >> 6;
    const int lane = tid & 63;
    const int o    = lane >> 2;
    const int cq   = lane & 3;

    float* PT = pose_t[wid];
    float* CP = coup_s[wid];
    float* G  = g_s[wid];

    // bijective chunked XCD swizzle over 1058 workgroups (q=132, r=2)
    const int bx  = blockIdx.x;
    const int xcd = bx & 7;
    const int sub = bx >> 3;
    const int wgs = (xcd < 2 ? xcd * 133 : 266 + (xcd - 2) * 132) + sub;
    const int n   = wgs * 4 + wid;

    const int b   = n / (46 * 46);
    const int rem = n - b * (46 * 46);
    const int ho  = rem / 46;
    const int wo  = rem - ho * 46;

    // ---- W row fragment: w01[ic]=(W[ic][o][cq][0],[1]), w23=([2],[3]) ----
    v2f w01[8], w23[8];
    #pragma unroll
    for (int i = 0; i < 8; ++i) {
        const v4f wv = *reinterpret_cast<const v4f*>(
            &Wg[((i * 16 + o) * 4 + cq) * 4]);
        w01[i] = lo2(wv);
        w23[i] = hi2(wv);
    }

    // ---- wave-local load of this pixel's 3x3 patch (9 x 136 ch) ----
    #pragma unroll
    for (int p = 0; p < 9; ++p) {
        const int py = p / 3, px = p - py * 3;
        const float* xr = &x[(((b * 48) + ho + py) * 48 + (wo + px)) * 136];
        #pragma unroll
        for (int t = 0; t < 3; ++t) {
            const int cc = lane + t * 64;
            if (t < 2 || cc < 136) {
                const float val = xr[cc];
                const int ic = (cc * 241) >> 12;       // cc/17 for cc<136
                const int aa = cc - ic * 17;
                const int k  = p * 8 + ic;
                if (aa == 16) PT[1216 + k] = val;      // act
                else          PT[aa * 76 + k] = val;
            }
        }
    }
    asm volatile("s_waitcnt lgkmcnt(0)" ::: "memory");

    float lreg[16];
    #pragma unroll
    for (int j = 0; j < 16; ++j) lreg[j] = 0.f;
    float lt0 = 0.f, lt1 = 0.f;   // tail logits (k=64+(lane>>3), o-pair lane&7)

    const int kT  = 64 + (lane >> 3);
    const int icT = lane >> 3;         // = kT & 7
    const int oT0 = (lane & 7) * 2;

    v2f va01[4], va23[4];              // squashed v[o][a][j], full per lane

    #pragma unroll 1
    for (int r = 0; r < 3; ++r) {
        // ---- phase B: M[ic][a] = sum_p coup[8p+ic][o] * pose[8p+ic][a*4+cq]
        const float* cb  = (r == 0) ? (PT + 1216) : (CP + o * 76);
        const float  msc = (r == 0) ? 0.0625f : 1.0f;
        v2f mac[4][4];   // [ic-pair][a]; pair m -> ic = 2m, 2m+1
        #pragma unroll
        for (int m = 0; m < 4; ++m)
            #pragma unroll
            for (int a = 0; a < 4; ++a) mac[m][a] = v2f{0.f, 0.f};
        #pragma unroll
        for (int p = 0; p < 9; ++p) {
            const v4f c0 = *reinterpret_cast<const v4f*>(cb + 8 * p);
            const v4f c1 = *reinterpret_cast<const v4f*>(cb + 8 * p + 4);
            #pragma unroll
            for (int a = 0; a < 4; ++a) {
                const v4f q0 = *reinterpret_cast<const v4f*>(
                    &PT[(a * 4 + cq) * 76 + 8 * p]);
                const v4f q1 = *reinterpret_cast<const v4f*>(
                    &PT[(a * 4 + cq) * 76 + 8 * p + 4]);
                mac[0][a] = fma2(lo2(c0), lo2(q0), mac[0][a]);
                mac[1][a] = fma2(hi2(c0), hi2(q0), mac[1][a]);
                mac[2][a] = fma2(lo2(c1), lo2(q1), mac[2][a]);
                mac[3][a] = fma2(hi2(c1), hi2(q1), mac[3][a]);
            }
        }
        // U[a][j] = sum_ic W[ic,o,cq,j] * M[ic][a]
        v2f U01[4], U23[4];
        #pragma unroll
        for (int a = 0; a < 4; ++a) { U01[a] = v2f{0.f,0.f}; U23[a] = v2f{0.f,0.f}; }
        #pragma unroll
        for (int m = 0; m < 4; ++m) {
            #pragma unroll
            for (int a = 0; a < 4; ++a) {
                const v2f m0 = { mac[m][a].x, mac[m][a].x };
                const v2f m1 = { mac[m][a].y, mac[m][a].y };
                U01[a] = fma2(w01[2*m],   m0, U01[a]);
                U23[a] = fma2(w23[2*m],   m0, U23[a]);
                U01[a] = fma2(w01[2*m+1], m1, U01[a]);
                U23[a] = fma2(w23[2*m+1], m1, U23[a]);
            }
        }
        // quad allreduce over cq (=b): Z[a*4+j] = s[o,a,j]
        float Z[16];
        #pragma unroll
        for (int a = 0; a < 4; ++a) {
            Z[a*4+0] = U01[a].x * msc;  Z[a*4+1] = U01[a].y * msc;
            Z[a*4+2] = U23[a].x * msc;  Z[a*4+3] = U23[a].y * msc;
        }
        #pragma unroll
        for (int j = 0; j < 16; ++j) {
            Z[j] += dpp_f<0xB1>(Z[j]);
            Z[j] += dpp_f<0x4E>(Z[j]);
        }
        // squash: fully lane-local (lane holds all 16 atoms of capsule o)
        float sq = 0.f;
        #pragma unroll
        for (int j = 0; j < 16; ++j) sq = fmaf(Z[j], Z[j], sq);
        const float ss = sq / ((1.f + sq) * sqrtf(sq + 1e-7f));
        #pragma unroll
        for (int a = 0; a < 4; ++a) {
            va01[a] = v2f{ Z[a*4+0] * ss, Z[a*4+1] * ss };
            va23[a] = v2f{ Z[a*4+2] * ss, Z[a*4+3] * ss };
        }

        if (r < 2) {
            // ---- G build (lane-local): G[ic,o,a*4+cq] = sum_j W[ic,o,cq,j]*v[a][j]
            #pragma unroll
            for (int ic = 0; ic < 8; ++ic) {
                #pragma unroll
                for (int a = 0; a < 4; ++a) {
                    const v2f h = fma2(w23[ic], va23[a], w01[ic] * va01[a]);
                    G[g_row(o, ic) + a * 4 + cq] = h.x + h.y;
                }
            }
            // pose columns + act for fused (PT is stable; issue before fence)
            float pc[16], pcT[16];
            #pragma unroll
            for (int j = 0; j < 16; ++j) pc[j]  = PT[j * 76 + lane];
            #pragma unroll
            for (int j = 0; j < 16; ++j) pcT[j] = PT[j * 76 + kT];
            const float actk = PT[1216 + lane];
            const float actT = PT[1216 + kT];
            asm volatile("s_waitcnt lgkmcnt(0)" ::: "memory");

            // ---- fused main: k = lane; delta[k][oo] = sum_e pose[k,e]*G[ic,oo,e]
            const int icM = lane & 7;
            const v2f q0 = {pc[0],  pc[1]},  q1 = {pc[2],  pc[3]};
            const v2f q2 = {pc[4],  pc[5]},  q3 = {pc[6],  pc[7]};
            const v2f q4 = {pc[8],  pc[9]},  q5 = {pc[10], pc[11]};
            const v2f q6 = {pc[12], pc[13]}, q7 = {pc[14], pc[15]};
            float lg[16];
            #pragma unroll
            for (int oo = 0; oo < 16; ++oo) {
                const v4f* gp = reinterpret_cast<const v4f*>(&G[g_row(oo, icM)]);
                const v4f g0 = gp[0], g1 = gp[1], g2 = gp[2], g3 = gp[3];
                const v2f A  = fma2(q2, lo2(g1), fma2(q4, lo2(g2),
                               fma2(q6, lo2(g3), q0 * lo2(g0))));
                const v2f Bv = fma2(q3, hi2(g1), fma2(q5, hi2(g2),
                               fma2(q7, hi2(g3), q1 * hi2(g0))));
                lreg[oo] += (A.x + A.y) + (Bv.x + Bv.y);
                lg[oo] = lreg[oo];
            }
            // softmax over 16 o, lane-local
            float mx = lg[0];
            #pragma unroll
            for (int j = 1; j < 16; ++j) mx = fmaxf(mx, lg[j]);
            float sum = 0.f;
            #pragma unroll
            for (int j = 0; j < 16; ++j) { lg[j] = __expf(lg[j] - mx); sum += lg[j]; }
            const float cs = actk / sum;
            #pragma unroll
            for (int oo = 0; oo < 16; ++oo) CP[oo * 76 + lane] = lg[oo] * cs;

            // ---- fused tail: k = 64+(lane>>3), o-pair = (lane&7)*2 ----
            {
                const v2f t0 = {pcT[0],  pcT[1]},  t1 = {pcT[2],  pcT[3]};
                const v2f t2 = {pcT[4],  pcT[5]},  t3 = {pcT[6],  pcT[7]};
                const v2f t4 = {pcT[8],  pcT[9]},  t5 = {pcT[10], pcT[11]};
                const v2f t6 = {pcT[12], pcT[13]}, t7 = {pcT[14], pcT[15]};
                {
                    const v4f* gp = reinterpret_cast<const v4f*>(&G[g_row(oT0, icT)]);
                    const v4f g0 = gp[0], g1 = gp[1], g2 = gp[2], g3 = gp[3];
                    const v2f A  = fma2(t2, lo2(g1), fma2(t4, lo2(g2),
                                   fma2(t6, lo2(g3), t0 * lo2(g0))));
                    const v2f Bv = fma2(t3, hi2(g1), fma2(t5, hi2(g2),
                                   fma2(t7, hi2(g3), t1 * hi2(g0))));
                    lt0 += (A.x + A.y) + (Bv.x + Bv.y);
                }
                {
                    const v4f* gp = reinterpret_cast<const v4f*>(&G[g_row(oT0 + 1, icT)]);
                    const v4f g0 = gp[0], g1 = gp[1], g2 = gp[2], g3 = gp[3];
                    const v2f A  = fma2(t2, lo2(g1), fma2(t4, lo2(g2),
                                   fma2(t6, lo2(g3), t0 * lo2(g0))));
                    const v2f Bv = fma2(t3, hi2(g1), fma2(t5, hi2(g2),
                                   fma2(t7, hi2(g3), t1 * hi2(g0))));
                    lt1 += (A.x + A.y) + (Bv.x + Bv.y);
                }
                // softmax over 16 o spread across the 8-lane group (2 per lane)
                float m2 = fmaxf(lt0, lt1);
                m2 = fmaxf(m2, swz<0x041F>(m2));   // xor 1
                m2 = fmaxf(m2, swz<0x081F>(m2));   // xor 2
                m2 = fmaxf(m2, swz<0x101F>(m2));   // xor 4
                const float e0 = __expf(lt0 - m2);
                const float e1 = __expf(lt1 - m2);
                float s2 = e0 + e1;
                s2 += swz<0x041F>(s2);
                s2 += swz<0x081F>(s2);
                s2 += swz<0x101F>(s2);
                const float csT = actT / s2;
                CP[oT0 * 76 + kT]       = e0 * csT;
                CP[(oT0 + 1) * 76 + kT] = e1 * csT;
            }
            asm volatile("s_waitcnt lgkmcnt(0)" ::: "memory");
        }
    }

    // ---- out[n][o][e=a*4+cq] = v[a][cq] ----
    #pragma unroll
    for (int a = 0; a < 4; ++a) {
        const float vo = (cq & 2) ? ((cq & 1) ? va23[a].y : va23[a].x)
                                  : ((cq & 1) ? va01[a].y : va01[a].x);
        out[n * 256 + o * 16 + a * 4 + cq] = vo;
    }
}

extern "C" void kernel_launch(void* const* d_in, const int* in_sizes, int n_in,
                              void* d_out, int out_size, void* d_ws, size_t ws_size,
                              hipStream_t stream) {
    const float* x  = (const float*)d_in[0];   // [2,48,48,136] fp32
    const float* Wt = (const float*)d_in[1];   // [8,16,4,4]    fp32
    float* outp = (float*)d_out;               // [2,46,46,16,16] fp32
    capsule_routing_kernel<<<dim3(NBLK), dim3(256), 0, stream>>>(x, Wt, outp);
}

// Round 8
// 89.860 us; speedup vs baseline: 1.0676x; 1.0591x over previous
//
#include <hip/hip_runtime.h>

// ConvCapsuleLayer: B=2, 48x48, IN_CAPS=8, ATOMS=16, KER=3, OUT_CAPS=16, R=3.
// Round-19: zero-barrier wave-per-pixel (r18) + LDS diet 81920->31232 B.
// r18 post-mortem: duty/wave rose 17->25% (structure works) but LDS capped
// residency at 8 waves/CU -> VALUBusy 30%. Cuts, structure-preserving:
//  - coup ALIASED into G buffer (disjoint live ranges within a wave; fused
//    reordered so ALL G reads precede CP writes; same-wave LDS ops are
//    in-order and compiler preserves may-alias order).
//  - 2 pixels / 128-thread block: 2x(1288+2616)x4 = 31232 B -> 5 blocks/CU
//    = 10 waves/CU (was 8), all waves independent.
//  - G stored as e'=b*4+a: G-build packs ds_write_b128 x8 (was b32 x32);
//    consumer re-pairs pc[] registers (same fma2 count, free).
//  - pose columns pc/pcT + act hoisted out of the r-loop (round-invariant).
// Guard: WRITE_SIZE ~4.2MB (no spill); VGPR may rise to ~140 (cap 3/SIMD >
// LDS cap 2.5 -> harmless).

#define NPIX 4232
#define NBLK 2116   // 2 pixels/block, 1 per wave

typedef float v2f __attribute__((ext_vector_type(2)));
typedef float v4f __attribute__((ext_vector_type(4)));

__device__ __forceinline__ v2f lo2(v4f v) { return __builtin_shufflevector(v, v, 0, 1); }
__device__ __forceinline__ v2f hi2(v4f v) { return __builtin_shufflevector(v, v, 2, 3); }
__device__ __forceinline__ v2f fma2(v2f a, v2f b, v2f c) {
    return __builtin_elementwise_fma(a, b, c);
}

template<int CTRL>
__device__ __forceinline__ float dpp_f(float x) {
    return __int_as_float(
        __builtin_amdgcn_update_dpp(0, __float_as_int(x), CTRL, 0xF, 0xF, true));
}
template<int OFF>
__device__ __forceinline__ float swz(float x) {
    return __int_as_float(__builtin_amdgcn_ds_swizzle(__float_as_int(x), OFF));
}

// G row start for (o, ic): stride 20 rows + 4*o skew (round-11 verified).
__device__ __forceinline__ int g_row(int o, int ic) {
    return (o * 8 + ic) * 20 + o * 4;
}

__global__ __launch_bounds__(128, 2)
void capsule_routing_kernel(const float* __restrict__ x,
                            const float* __restrict__ Wg,
                            float* __restrict__ out)
{
    // per-pixel: pose_t [aa][k] stride 76 (1216) + act[72] @1216 -> 1288
    //            GB: G (2616 floats) with coup ALIASED at GB[0..1216)
    __shared__ alignas(16) float pose_t[2][1288];   // 10304 B
    __shared__ alignas(16) float g_buf[2][2616];    // 20928 B
    // total 31232 B -> 5 blocks/CU (10 independent waves)

    const int tid  = threadIdx.x;
    const int wid  = tid >> 6;
    const int lane = tid & 63;
    const int o    = lane >> 2;
    const int cq   = lane & 3;

    float* PT = pose_t[wid];
    float* GB = g_buf[wid];

    // bijective chunked XCD swizzle over 2116 workgroups (q=264, r=4)
    const int bx  = blockIdx.x;
    const int xcd = bx & 7;
    const int sub = bx >> 3;
    const int wgs = (xcd < 4 ? xcd * 265 : 1060 + (xcd - 4) * 264) + sub;
    const int n   = wgs * 2 + wid;

    const int b   = n / (46 * 46);
    const int rem = n - b * (46 * 46);
    const int ho  = rem / 46;
    const int wo  = rem - ho * 46;

    // ---- W row fragment: w01[ic]=(W[ic][o][cq][0],[1]), w23=([2],[3]) ----
    v2f w01[8], w23[8];
    #pragma unroll
    for (int i = 0; i < 8; ++i) {
        const v4f wv = *reinterpret_cast<const v4f*>(
            &Wg[((i * 16 + o) * 4 + cq) * 4]);
        w01[i] = lo2(wv);
        w23[i] = hi2(wv);
    }

    // ---- wave-local load of this pixel's 3x3 patch (9 x 136 ch) ----
    #pragma unroll
    for (int p = 0; p < 9; ++p) {
        const int py = p / 3, px = p - py * 3;
        const float* xr = &x[(((b * 48) + ho + py) * 48 + (wo + px)) * 136];
        #pragma unroll
        for (int t = 0; t < 3; ++t) {
            const int cc = lane + t * 64;
            if (t < 2 || cc < 136) {
                const float val = xr[cc];
                const int ic = (cc * 241) >> 12;       // cc/17 for cc<136
                const int aa = cc - ic * 17;
                const int k  = p * 8 + ic;
                if (aa == 16) PT[1216 + k] = val;      // act
                else          PT[aa * 76 + k] = val;
            }
        }
    }
    asm volatile("s_waitcnt lgkmcnt(0)" ::: "memory");

    const int kT  = 64 + (lane >> 3);
    const int icT = lane >> 3;         // = kT & 7
    const int oT0 = (lane & 7) * 2;
    const int icM = lane & 7;

    // ---- round-invariant pose columns + act, hoisted (registers) ----
    float pc[16], pcT[16];
    #pragma unroll
    for (int j = 0; j < 16; ++j) pc[j]  = PT[j * 76 + lane];
    #pragma unroll
    for (int j = 0; j < 16; ++j) pcT[j] = PT[j * 76 + kT];
    const float actk = PT[1216 + lane];
    const float actT = PT[1216 + kT];
    asm volatile("s_waitcnt lgkmcnt(0)" ::: "memory");

    float lreg[16];
    #pragma unroll
    for (int j = 0; j < 16; ++j) lreg[j] = 0.f;
    float lt0 = 0.f, lt1 = 0.f;

    v2f va01[4], va23[4];              // squashed v[o][a][j], full per lane

    // dot of a pose-column (16 regs) against one G' row (4 chunks, e'=b*4+a)
    #define GDOT(P, gp, accum) do {                                          \
        const v4f b0 = (gp)[0], b1 = (gp)[1], b2 = (gp)[2], b3 = (gp)[3];    \
        v2f acc2 = {0.f, 0.f};                                               \
        acc2 = fma2(v2f{(P)[0], (P)[4]},  lo2(b0), acc2);                    \
        acc2 = fma2(v2f{(P)[8], (P)[12]}, hi2(b0), acc2);                    \
        acc2 = fma2(v2f{(P)[1], (P)[5]},  lo2(b1), acc2);                    \
        acc2 = fma2(v2f{(P)[9], (P)[13]}, hi2(b1), acc2);                    \
        acc2 = fma2(v2f{(P)[2], (P)[6]},  lo2(b2), acc2);                    \
        acc2 = fma2(v2f{(P)[10],(P)[14]}, hi2(b2), acc2);                    \
        acc2 = fma2(v2f{(P)[3], (P)[7]},  lo2(b3), acc2);                    \
        acc2 = fma2(v2f{(P)[11],(P)[15]}, hi2(b3), acc2);                    \
        accum += acc2.x + acc2.y;                                            \
    } while (0)

    #pragma unroll 1
    for (int r = 0; r < 3; ++r) {
        // ---- phase B: M[ic][a] = sum_p coup[8p+ic][o] * pose[8p+ic][a*4+cq]
        const float* cb  = (r == 0) ? (PT + 1216) : (GB + o * 76);
        const float  msc = (r == 0) ? 0.0625f : 1.0f;
        v2f mac[4][4];   // [ic-pair][a]
        #pragma unroll
        for (int m = 0; m < 4; ++m)
            #pragma unroll
            for (int a = 0; a < 4; ++a) mac[m][a] = v2f{0.f, 0.f};
        #pragma unroll
        for (int p = 0; p < 9; ++p) {
            const v4f c0 = *reinterpret_cast<const v4f*>(cb + 8 * p);
            const v4f c1 = *reinterpret_cast<const v4f*>(cb + 8 * p + 4);
            #pragma unroll
            for (int a = 0; a < 4; ++a) {
                const v4f q0 = *reinterpret_cast<const v4f*>(
                    &PT[(a * 4 + cq) * 76 + 8 * p]);
                const v4f q1 = *reinterpret_cast<const v4f*>(
                    &PT[(a * 4 + cq) * 76 + 8 * p + 4]);
                mac[0][a] = fma2(lo2(c0), lo2(q0), mac[0][a]);
                mac[1][a] = fma2(hi2(c0), hi2(q0), mac[1][a]);
                mac[2][a] = fma2(lo2(c1), lo2(q1), mac[2][a]);
                mac[3][a] = fma2(hi2(c1), hi2(q1), mac[3][a]);
            }
        }
        // U[a][j] = sum_ic W[ic,o,cq,j] * M[ic][a]
        v2f U01[4], U23[4];
        #pragma unroll
        for (int a = 0; a < 4; ++a) { U01[a] = v2f{0.f,0.f}; U23[a] = v2f{0.f,0.f}; }
        #pragma unroll
        for (int m = 0; m < 4; ++m) {
            #pragma unroll
            for (int a = 0; a < 4; ++a) {
                const v2f m0 = { mac[m][a].x, mac[m][a].x };
                const v2f m1 = { mac[m][a].y, mac[m][a].y };
                U01[a] = fma2(w01[2*m],   m0, U01[a]);
                U23[a] = fma2(w23[2*m],   m0, U23[a]);
                U01[a] = fma2(w01[2*m+1], m1, U01[a]);
                U23[a] = fma2(w23[2*m+1], m1, U23[a]);
            }
        }
        // quad allreduce over cq (=b): Z[a*4+j] = s[o,a,j]
        float Z[16];
        #pragma unroll
        for (int a = 0; a < 4; ++a) {
            Z[a*4+0] = U01[a].x * msc;  Z[a*4+1] = U01[a].y * msc;
            Z[a*4+2] = U23[a].x * msc;  Z[a*4+3] = U23[a].y * msc;
        }
        #pragma unroll
        for (int j = 0; j < 16; ++j) {
            Z[j] += dpp_f<0xB1>(Z[j]);
            Z[j] += dpp_f<0x4E>(Z[j]);
        }
        // squash: fully lane-local
        float sq = 0.f;
        #pragma unroll
        for (int j = 0; j < 16; ++j) sq = fmaf(Z[j], Z[j], sq);
        const float ss = sq / ((1.f + sq) * sqrtf(sq + 1e-7f));
        #pragma unroll
        for (int a = 0; a < 4; ++a) {
            va01[a] = v2f{ Z[a*4+0] * ss, Z[a*4+1] * ss };
            va23[a] = v2f{ Z[a*4+2] * ss, Z[a*4+3] * ss };
        }

        if (r < 2) {
            // ---- G build, e'=b*4+a packing: one b128 store per ic ----
            #pragma unroll
            for (int ic = 0; ic < 8; ++ic) {
                v4f gv;
                #pragma unroll
                for (int a = 0; a < 4; ++a) {
                    const v2f h = fma2(w23[ic], va23[a], w01[ic] * va01[a]);
                    gv[a] = h.x + h.y;
                }
                *reinterpret_cast<v4f*>(&GB[g_row(o, ic) + cq * 4]) = gv;
            }
            asm volatile("s_waitcnt lgkmcnt(0)" ::: "memory");

            // ---- fused: ALL G reads first (main + tail), then CP writes ----
            float lg[16];
            #pragma unroll
            for (int oo = 0; oo < 16; ++oo) {
                const v4f* gp = reinterpret_cast<const v4f*>(&GB[g_row(oo, icM)]);
                GDOT(pc, gp, lreg[oo]);
                lg[oo] = lreg[oo];
            }
            {
                const v4f* gp0 = reinterpret_cast<const v4f*>(&GB[g_row(oT0, icT)]);
                GDOT(pcT, gp0, lt0);
                const v4f* gp1 = reinterpret_cast<const v4f*>(&GB[g_row(oT0 + 1, icT)]);
                GDOT(pcT, gp1, lt1);
            }

            // main softmax over 16 o (lane-local) -> CP writes (alias GB)
            float mx = lg[0];
            #pragma unroll
            for (int j = 1; j < 16; ++j) mx = fmaxf(mx, lg[j]);
            float sum = 0.f;
            #pragma unroll
            for (int j = 0; j < 16; ++j) { lg[j] = __expf(lg[j] - mx); sum += lg[j]; }
            const float cs = actk / sum;
            #pragma unroll
            for (int oo = 0; oo < 16; ++oo) GB[oo * 76 + lane] = lg[oo] * cs;

            // tail softmax over 16 o spread across 8-lane group (2 per lane)
            {
                float m2 = fmaxf(lt0, lt1);
                m2 = fmaxf(m2, swz<0x041F>(m2));
                m2 = fmaxf(m2, swz<0x081F>(m2));
                m2 = fmaxf(m2, swz<0x101F>(m2));
                const float e0 = __expf(lt0 - m2);
                const float e1 = __expf(lt1 - m2);
                float s2 = e0 + e1;
                s2 += swz<0x041F>(s2);
                s2 += swz<0x081F>(s2);
                s2 += swz<0x101F>(s2);
                const float csT = actT / s2;
                GB[oT0 * 76 + kT]       = e0 * csT;
                GB[(oT0 + 1) * 76 + kT] = e1 * csT;
                lt0 = lt0; lt1 = lt1;
            }
            asm volatile("s_waitcnt lgkmcnt(0)" ::: "memory");
        }
    }

    // ---- out[n][o][e=a*4+cq] = v[a][cq] ----
    #pragma unroll
    for (int a = 0; a < 4; ++a) {
        const float vo = (cq & 2) ? ((cq & 1) ? va23[a].y : va23[a].x)
                                  : ((cq & 1) ? va01[a].y : va01[a].x);
        out[n * 256 + o * 16 + a * 4 + cq] = vo;
    }
}

extern "C" void kernel_launch(void* const* d_in, const int* in_sizes, int n_in,
                              void* d_out, int out_size, void* d_ws, size_t ws_size,
                              hipStream_t stream) {
    const float* x  = (const float*)d_in[0];   // [2,48,48,136] fp32
    const float* Wt = (const float*)d_in[1];   // [8,16,4,4]    fp32
    float* outp = (float*)d_out;               // [2,46,46,16,16] fp32
    capsule_routing_kernel<<<dim3(NBLK), dim3(128), 0, stream>>>(x, Wt, outp);
}